// Round 10
// baseline (1976.639 us; speedup 1.0000x reference)
//
#include <hip/hip_runtime.h>
#include <hip/hip_cooperative_groups.h>
#include <math.h>

namespace cg = cooperative_groups;

#define B_ 2048
#define T_ 16
#define F_ 512
#define U_ 512
#define M_ 8

typedef _Float16 half8 __attribute__((ext_vector_type(8)));
typedef float f32x4 __attribute__((ext_vector_type(4)));

__device__ __forceinline__ void load_lds16(const _Float16* gsrc, _Float16* lds) {
    __builtin_amdgcn_global_load_lds(
        (const __attribute__((address_space(1))) void*)gsrc,
        (__attribute__((address_space(3))) void*)lds, 16, 0, 0);
}

#define BAR() __builtin_amdgcn_s_barrier()
#define LGKM0() asm volatile("s_waitcnt lgkmcnt(0)" ::: "memory")
#define VMW(n) asm volatile("s_waitcnt vmcnt(" #n ")" ::: "memory")
#define MFMA16(a, b, c) __builtin_amdgcn_mfma_f32_16x16x32_f16(a, b, c, 0, 0, 0)

struct Decay8 { float d[8]; };

// ---------------- prep kernels ----------------
__global__ __launch_bounds__(256) void cast_x_kernel(const float* __restrict__ in,
                                                     _Float16* __restrict__ out) {
    long i = (long)blockIdx.x * 256 + threadIdx.x;
    const f32x4* p = (const f32x4*)in;
    f32x4 a = p[i * 2], b = p[i * 2 + 1];
    half8 v;
    v[0] = (_Float16)a[0]; v[1] = (_Float16)a[1]; v[2] = (_Float16)a[2]; v[3] = (_Float16)a[3];
    v[4] = (_Float16)b[0]; v[5] = (_Float16)b[1]; v[6] = (_Float16)b[2]; v[7] = (_Float16)b[3];
    ((half8*)out)[i] = v;
}

__global__ __launch_bounds__(256) void transpose_cast_kernel(const float* __restrict__ W,
                                                             _Float16* __restrict__ Wt,
                                                             int K, int N) {
    __shared__ float tile[32][33];
    int n0 = blockIdx.x * 32, k0 = blockIdx.y * 32;
    int tx = threadIdx.x, ty = threadIdx.y;
    #pragma unroll
    for (int i = 0; i < 32; i += 8)
        tile[ty + i][tx] = W[(long)(k0 + ty + i) * N + n0 + tx];
    __syncthreads();
    #pragma unroll
    for (int i = 0; i < 32; i += 8)
        Wt[(long)(n0 + ty + i) * K + k0 + tx] = (_Float16)tile[tx][ty + i];
}

// Permuted W_r/W_s: col n=(u*8+tau) -> row (u>>4)*128 + tau*16 + (u&15)
__global__ __launch_bounds__(256) void transpose_cast_perm_kernel(const float* __restrict__ W,
                                                                  _Float16* __restrict__ Wt,
                                                                  int rowbase) {
    const int K = 1024, N = 4096;
    __shared__ float tile[32][33];
    int n0 = blockIdx.x * 32, k0 = blockIdx.y * 32;
    int tx = threadIdx.x, ty = threadIdx.y;
    #pragma unroll
    for (int i = 0; i < 32; i += 8)
        tile[ty + i][tx] = W[(long)(k0 + ty + i) * N + n0 + tx];
    __syncthreads();
    #pragma unroll
    for (int i = 0; i < 32; i += 8) {
        int nl = n0 + ty + i;
        int u = nl >> 3, m = nl & 7;
        int nn = ((u >> 4) << 7) + (m << 4) + (u & 15);
        Wt[(long)(rowbase + nn) * K + k0 + tx] = (_Float16)tile[tx][ty + i];
    }
}

// ---------------- persistent mega kernel: 16 steps of {gemm1 -> sync -> gemm2 -> sync}
// gemm1: 256x256 tile, 8 waves, 8-phase counted-vmcnt, fused softmax epilogue.
// gemm2: 64x64 tile, 8 waves, dbuf, fused state-update epilogue.
// LDS map (f16 units): AS0 0..16K, AS1 16K..32K, BS0 32K..48K, BS1 48K..64K;
// gemm2's A2/B2 live inside BS1 (49152.. / 57344..). Prologue of step t+1 (12 calls
// touching AS0/AS1/BS0 only) is hoisted into gemm2(t); the 2 BS1 calls are deferred
// to the top of gemm1(t+1). ----------------------------------------------------------
__global__ __launch_bounds__(512, 1) void ctgru_mega(
    const _Float16* __restrict__ x_all,   // (B, T*F)
    const _Float16* __restrict__ Wrs,     // 8192 x 1024 (permuted)
    const _Float16* __restrict__ Wq,      // 512 x 1024
    const float* __restrict__ b_r, const float* __restrict__ b_s,
    const float* __restrict__ b_q,
    _Float16* __restrict__ h_hat,         // (B,4096), zero-initialized
    _Float16* __restrict__ ctx,           // (B,512)
    _Float16* __restrict__ s_buf,         // (B,4096)
    _Float16* __restrict__ hs,            // (T,B,512)
    Decay8 dec) {
    cg::grid_group grid = cg::this_grid();
    const float LT = 1.1512925464970228f;
    __shared__ __align__(16) _Float16 lds[65536];   // 128 KB
#define AS(b_) (lds + (b_) * 16384)
#define BS(b_) (lds + 32768 + (b_) * 16384)
#define A2(b_) (lds + 49152 + (b_) * 4096)
#define B2(b_) (lds + 57344 + (b_) * 4096)
    const int tid = threadIdx.x;
    const int lane = tid & 63;
    const int wave = tid >> 6;
    const int wm = wave >> 1, wn = wave & 1;
    const int l15 = lane & 15, lhi = lane >> 4, swz = lane & 7;
    const int g0 = (lhi ^ swz) * 8;
    const int g1 = ((lhi + 4) ^ swz) * 8;
    const int srow = tid >> 3;
    const int sg = (tid & 7) ^ (srow & 7);
    const int ldsdst = wave * 512;
    const int bid = blockIdx.x;
    const int bx = bid & 31, by = bid >> 5;            // gemm1 role
    const long m1 = (long)by * 256, n1 = (long)bx * 256;
    const int gx = bid & 7, gy = bid >> 3;             // gemm2 role
    const long m2 = (long)gy * 64, n2 = (long)gx * 64;
    const long ldax = (long)T_ * F_;

#define STG1_A(kt_, buf_, r_) do {                                              \
        int kk_ = (kt_);                                                        \
        const _Float16* s_; long lda_; int ko_;                                 \
        if (kk_ < 8) { s_ = A0; lda_ = ldax; ko_ = kk_ * 64; }                  \
        else         { s_ = A1; lda_ = 512;  ko_ = kk_ * 64 - 512; }            \
        load_lds16(s_ + (m1 + (r_) * 64 + srow) * lda_ + ko_ + sg * 8,          \
                   AS(buf_) + (r_) * 4096 + ldsdst);                            \
    } while (0)
#define STG1_B(kt_, buf_, r_)                                                   \
        load_lds16(Wrs + (n1 + (r_) * 64 + srow) * 1024 + (kt_) * 64 + sg * 8,  \
                   BS(buf_) + (r_) * 4096 + ldsdst)

    #pragma unroll 1
    for (int t = 0; t < T_; ++t) {
        const int nt = (t == 0) ? 8 : 16;
        const _Float16* A0 = x_all + (long)t * F_;
        const _Float16* A1 = hs + (size_t)(t - 1) * B_ * U_;   // valid for t>=1
        const bool act = (t > 0) || (bx >= 16);     // t=0: ctx==0, skip r-panels

        // ================= GEMM1 phase =================
        if (act) {
            if (t == 0) {
                #pragma unroll
                for (int r = 0; r < 4; ++r) STG1_A(0, 0, r);
                #pragma unroll
                for (int r = 0; r < 4; ++r) STG1_B(0, 0, r);
                #pragma unroll
                for (int r = 0; r < 4; ++r) STG1_A(1, 1, r);
                STG1_B(1, 1, 0); STG1_B(1, 1, 2);
            } else {
                STG1_B(1, 1, 0); STG1_B(1, 1, 2);   // rest hoisted during gemm2(t-1)
            }
            VMW(6);
            BAR();

            f32x4 acc[4][8] = {};
            #pragma unroll 1
            for (int it = 0; it < nt; ++it) {
                const int cur = it & 1, nxt = cur ^ 1;
                const _Float16* Ac = AS(cur);
                const _Float16* Bc = BS(cur);
                half8 af[4][2], bfa[2][2], bfb[2][2];

                // ---- P0 ----
                #pragma unroll
                for (int i = 0; i < 4; ++i) {
                    const _Float16* p = Ac + (wm * 64 + i * 16 + l15) * 64;
                    af[i][0] = *(const half8*)(p + g0);
                    af[i][1] = *(const half8*)(p + g1);
                }
                #pragma unroll
                for (int j = 0; j < 2; ++j) {
                    const _Float16* p = Bc + (wn * 128 + j * 16 + l15) * 64;
                    bfa[j][0] = *(const half8*)(p + g0);
                    bfa[j][1] = *(const half8*)(p + g1);
                }
                if (it + 1 < nt) { STG1_B(it + 1, nxt, 1); STG1_B(it + 1, nxt, 3); }
                LGKM0();
                __builtin_amdgcn_s_setprio(1);
                #pragma unroll
                for (int i = 0; i < 4; ++i)
                    #pragma unroll
                    for (int j = 0; j < 2; ++j) {
                        acc[i][j] = MFMA16(af[i][0], bfa[j][0], acc[i][j]);
                        acc[i][j] = MFMA16(af[i][1], bfa[j][1], acc[i][j]);
                    }
                __builtin_amdgcn_s_setprio(0);
                BAR();

                // ---- P1 ----
                #pragma unroll
                for (int j = 0; j < 2; ++j) {
                    const _Float16* p = Bc + (wn * 128 + (2 + j) * 16 + l15) * 64;
                    bfb[j][0] = *(const half8*)(p + g0);
                    bfb[j][1] = *(const half8*)(p + g1);
                }
                if (it + 2 < nt) { STG1_A(it + 2, cur, 0); STG1_A(it + 2, cur, 1); }
                BAR(); LGKM0();
                __builtin_amdgcn_s_setprio(1);
                #pragma unroll
                for (int i = 0; i < 4; ++i)
                    #pragma unroll
                    for (int j = 0; j < 2; ++j) {
                        acc[i][2 + j] = MFMA16(af[i][0], bfb[j][0], acc[i][2 + j]);
                        acc[i][2 + j] = MFMA16(af[i][1], bfb[j][1], acc[i][2 + j]);
                    }
                __builtin_amdgcn_s_setprio(0);
                BAR();

                // ---- P2 ----
                #pragma unroll
                for (int j = 0; j < 2; ++j) {
                    const _Float16* p = Bc + (wn * 128 + (4 + j) * 16 + l15) * 64;
                    bfa[j][0] = *(const half8*)(p + g0);
                    bfa[j][1] = *(const half8*)(p + g1);
                }
                if (it + 2 < nt) { STG1_A(it + 2, cur, 2); STG1_A(it + 2, cur, 3); }
                LGKM0();
                __builtin_amdgcn_s_setprio(1);
                #pragma unroll
                for (int i = 0; i < 4; ++i)
                    #pragma unroll
                    for (int j = 0; j < 2; ++j) {
                        acc[i][4 + j] = MFMA16(af[i][0], bfa[j][0], acc[i][4 + j]);
                        acc[i][4 + j] = MFMA16(af[i][1], bfa[j][1], acc[i][4 + j]);
                    }
                __builtin_amdgcn_s_setprio(0);
                BAR();

                // ---- P3 ----
                #pragma unroll
                for (int j = 0; j < 2; ++j) {
                    const _Float16* p = Bc + (wn * 128 + (6 + j) * 16 + l15) * 64;
                    bfb[j][0] = *(const half8*)(p + g0);
                    bfb[j][1] = *(const half8*)(p + g1);
                }
                if (it + 2 < nt) { STG1_B(it + 2, cur, 0); STG1_B(it + 2, cur, 2); }
                LGKM0();
                __builtin_amdgcn_s_setprio(1);
                #pragma unroll
                for (int i = 0; i < 4; ++i)
                    #pragma unroll
                    for (int j = 0; j < 2; ++j) {
                        acc[i][6 + j] = MFMA16(af[i][0], bfb[j][0], acc[i][6 + j]);
                        acc[i][6 + j] = MFMA16(af[i][1], bfb[j][1], acc[i][6 + j]);
                    }
                __builtin_amdgcn_s_setprio(0);
                if (it + 2 < nt)      { VMW(6); }
                else if (it + 1 < nt) { VMW(0); }
                BAR();
            }

            // ---- fused epilogue: thread-local softmax over 8 taus ----
            const int r4 = lhi * 4;
            const int panel = (int)(n1 >> 7) + wn;
            const bool is_r = panel < 32;
            const int u = (is_r ? panel : panel - 32) * 16 + l15;
            const float* bias = is_r ? b_r : b_s;
            f32x4 bl0 = *(const f32x4*)(bias + u * 8);
            f32x4 bl1 = *(const f32x4*)(bias + u * 8 + 4);
            #pragma unroll
            for (int i = 0; i < 4; ++i) {
                #pragma unroll
                for (int r = 0; r < 4; ++r) {
                    long m = m1 + wm * 64 + i * 16 + r4 + r;
                    float z[8]; float zmax = -1e30f;
                    #pragma unroll
                    for (int j = 0; j < 8; ++j) {
                        float v = acc[i][j][r] + (j < 4 ? bl0[j] : bl1[j - 4]);
                        float d = v - (float)j * LT;
                        z[j] = -d * d;
                        zmax = fmaxf(zmax, z[j]);
                    }
                    float e[8]; float se = 0.f;
                    #pragma unroll
                    for (int j = 0; j < 8; ++j) { e[j] = __expf(z[j] - zmax); se += e[j]; }
                    float inv = 1.f / se;
                    if (is_r) {
                        half8 hh = *(const half8*)(h_hat + m * 4096 + u * 8);
                        float c = 0.f;
                        #pragma unroll
                        for (int j = 0; j < 8; ++j) c += e[j] * (float)hh[j];
                        ctx[m * 512 + u] = (_Float16)(c * inv);
                    } else {
                        half8 sv;
                        #pragma unroll
                        for (int j = 0; j < 8; ++j) sv[j] = (_Float16)(e[j] * inv);
                        *(half8*)(s_buf + m * 4096 + u * 8) = sv;
                    }
                }
            }
        }
        grid.sync();

        // ================= GEMM2 phase =================
        {
            _Float16* hs_t = hs + (size_t)t * B_ * U_;
#define STG2(kt_, buf_) do {                                                    \
            int kk_ = (kt_);                                                    \
            const _Float16* s_; long lda_; int ko_;                             \
            if (kk_ < 8) { s_ = A0;  lda_ = ldax; ko_ = kk_ * 64; }             \
            else         { s_ = ctx; lda_ = 512;  ko_ = kk_ * 64 - 512; }       \
            load_lds16(s_ + (m2 + srow) * lda_ + ko_ + sg * 8,                  \
                       A2(buf_) + wave * 512);                                  \
            load_lds16(Wq + (n2 + srow) * 1024 + kk_ * 64 + sg * 8,             \
                       B2(buf_) + wave * 512);                                  \
        } while (0)

            f32x4 acc2[2] = {};
            STG2(0, 0);
            #pragma unroll 1
            for (int kt = 0; kt < nt; ++kt) {
                const int cur = kt & 1;
                if (kt + 1 < nt) { STG2(kt + 1, cur ^ 1); VMW(2); }
                else             { VMW(0); }
                BAR();
                const _Float16* Ac = A2(cur);
                const _Float16* Bc = B2(cur);
                half8 af[2], bf[2][2];
                {
                    const _Float16* p = Ac + (wm * 16 + l15) * 64;
                    af[0] = *(const half8*)(p + g0);
                    af[1] = *(const half8*)(p + g1);
                }
                #pragma unroll
                for (int j = 0; j < 2; ++j) {
                    const _Float16* p = Bc + (wn * 32 + j * 16 + l15) * 64;
                    bf[j][0] = *(const half8*)(p + g0);
                    bf[j][1] = *(const half8*)(p + g1);
                }
                LGKM0();
                #pragma unroll
                for (int j = 0; j < 2; ++j) {
                    acc2[j] = MFMA16(af[0], bf[j][0], acc2[j]);
                    acc2[j] = MFMA16(af[1], bf[j][1], acc2[j]);
                }
                BAR();
            }
#undef STG2

            const int r4 = lhi * 4;
            #pragma unroll
            for (int j = 0; j < 2; ++j) {
                #pragma unroll
                for (int r = 0; r < 4; ++r) {
                    long b = m2 + wm * 16 + r4 + r;
                    long u = n2 + wn * 32 + j * 16 + l15;
                    float q = tanhf(acc2[j][r] + b_q[u]);
                    half8 s8 = *(const half8*)(s_buf + b * 4096 + u * 8);
                    half8 h8 = *(const half8*)(h_hat + b * 4096 + u * 8);
                    half8 hn;
                    float hval = 0.f;
                    #pragma unroll
                    for (int m = 0; m < 8; ++m) {
                        float sm = (float)s8[m];
                        float x = ((1.f - sm) * (float)h8[m] + sm * q) * dec.d[m];
                        hn[m] = (_Float16)x;
                        hval += x;
                    }
                    *(half8*)(h_hat + b * 4096 + u * 8) = hn;
                    hs_t[b * 512 + u] = (_Float16)hval;
                }
            }
        }

        // ---- hoist gemm1(t+1) prologue (AS0/AS1/BS0 only; no hs dependency) ----
        if (t + 1 < T_) {
            const _Float16* A0n = x_all + (long)(t + 1) * F_;
            #pragma unroll
            for (int r = 0; r < 4; ++r)
                load_lds16(A0n + (m1 + r * 64 + srow) * ldax + sg * 8,
                           AS(0) + r * 4096 + ldsdst);
            #pragma unroll
            for (int r = 0; r < 4; ++r)
                load_lds16(Wrs + (n1 + r * 64 + srow) * 1024 + sg * 8,
                           BS(0) + r * 4096 + ldsdst);
            #pragma unroll
            for (int r = 0; r < 4; ++r)
                load_lds16(A0n + (m1 + r * 64 + srow) * ldax + 64 + sg * 8,
                           AS(1) + r * 4096 + ldsdst);
            grid.sync();
        }
    }
#undef STG1_A
#undef STG1_B
#undef AS
#undef BS
#undef A2
#undef B2
}

// ---------------- final: out[b][t] = hs[t][b] @ W_o + b_o ----------------
__global__ __launch_bounds__(64) void out_proj_kernel(const _Float16* __restrict__ hs,
                                                      const float* __restrict__ W_o,
                                                      const float* __restrict__ b_o,
                                                      float* __restrict__ out) {
    const int bt = blockIdx.x;
    const int t = bt >> 11, b = bt & 2047;
    const int lane = threadIdx.x;
    half8 v = *(const half8*)(hs + ((long)t * 2048 + b) * 512 + lane * 8);
    float p0 = 0.f, p1 = 0.f, p2 = 0.f;
    #pragma unroll
    for (int m = 0; m < 8; ++m) {
        float hv = (float)v[m];
        int u = lane * 8 + m;
        p0 += hv * W_o[u * 3 + 0];
        p1 += hv * W_o[u * 3 + 1];
        p2 += hv * W_o[u * 3 + 2];
    }
    #pragma unroll
    for (int s = 32; s > 0; s >>= 1) {
        p0 += __shfl_down(p0, s);
        p1 += __shfl_down(p1, s);
        p2 += __shfl_down(p2, s);
    }
    if (lane == 0) {
        long o = ((long)b * T_ + t) * 3;
        out[o + 0] = p0 + b_o[0];
        out[o + 1] = p1 + b_o[1];
        out[o + 2] = p2 + b_o[2];
    }
}

// ---------------- host ----------------
extern "C" void kernel_launch(void* const* d_in, const int* in_sizes, int n_in,
                              void* d_out, int out_size, void* d_ws, size_t ws_size,
                              hipStream_t stream) {
    const float* x   = (const float*)d_in[0];
    const float* W_r = (const float*)d_in[1];
    const float* b_r = (const float*)d_in[2];
    const float* W_q = (const float*)d_in[3];
    const float* b_q = (const float*)d_in[4];
    const float* W_s = (const float*)d_in[5];
    const float* b_s = (const float*)d_in[6];
    const float* W_o = (const float*)d_in[7];
    const float* b_o = (const float*)d_in[8];
    float* out = (float*)d_out;

    char* ws = (char*)d_ws;
    size_t off = 0;
    _Float16* x_h   = (_Float16*)(ws + off); off += (size_t)B_ * T_ * F_ * 2;     // 33.5 MB
    _Float16* Wrs_t = (_Float16*)(ws + off); off += (size_t)8192 * 1024 * 2;      // 16.8 MB
    _Float16* Wq_t  = (_Float16*)(ws + off); off += (size_t)512 * 1024 * 2;       // 1 MB
    _Float16* s_buf = (_Float16*)(ws + off); off += (size_t)B_ * 4096 * 2;        // 16.8 MB
    _Float16* h_hat = (_Float16*)(ws + off); off += (size_t)B_ * 4096 * 2;        // 16.8 MB
    _Float16* ctx_h = (_Float16*)(ws + off); off += (size_t)B_ * U_ * 2;          // 2 MB
    _Float16* hs    = (_Float16*)(ws + off); off += (size_t)T_ * B_ * U_ * 2;     // 33.5 MB
    if (ws_size < off) return;

    hipMemsetAsync(h_hat, 0, (size_t)B_ * 4096 * 2, stream);

    cast_x_kernel<<<dim3((B_ * T_ * F_) / (256 * 8)), 256, 0, stream>>>(x, x_h);
    transpose_cast_perm_kernel<<<dim3(4096 / 32, 1024 / 32), dim3(32, 8), 0, stream>>>(W_r, Wrs_t, 0);
    transpose_cast_perm_kernel<<<dim3(4096 / 32, 1024 / 32), dim3(32, 8), 0, stream>>>(W_s, Wrs_t, 4096);
    transpose_cast_kernel<<<dim3(512 / 32, 1024 / 32), dim3(32, 8), 0, stream>>>(W_q, Wq_t, 1024, 512);

    Decay8 dec;
    for (int m = 0; m < 8; ++m) {
        float lt = (float)m * 1.1512925464970228f;
        dec.d[m] = expf(-0.04f / (expf(lt) + 1e-7f));
    }

    void* kargs[] = {(void*)&x_h, (void*)&Wrs_t, (void*)&Wq_t,
                     (void*)&b_r, (void*)&b_s, (void*)&b_q,
                     (void*)&h_hat, (void*)&ctx_h, (void*)&s_buf, (void*)&hs,
                     (void*)&dec};
    hipLaunchCooperativeKernel((void*)ctgru_mega, dim3(256), dim3(512),
                               kargs, 0, stream);

    out_proj_kernel<<<dim3(B_ * T_), 64, 0, stream>>>(hs, W_o, b_o, out);
    (void)in_sizes; (void)n_in; (void)out_size;
}

// Round 11
// 1331.841 us; speedup vs baseline: 1.4841x; 1.4841x over previous
//
#include <hip/hip_runtime.h>
#include <math.h>

#define B_ 2048
#define T_ 16
#define F_ 512
#define U_ 512
#define M_ 8

typedef _Float16 half8 __attribute__((ext_vector_type(8)));
typedef float f32x4 __attribute__((ext_vector_type(4)));

__device__ __forceinline__ void load_lds16(const _Float16* gsrc, _Float16* lds) {
    __builtin_amdgcn_global_load_lds(
        (const __attribute__((address_space(1))) void*)gsrc,
        (__attribute__((address_space(3))) void*)lds, 16, 0, 0);
}

#define BAR() __builtin_amdgcn_s_barrier()
#define LGKM0() asm volatile("s_waitcnt lgkmcnt(0)" ::: "memory")
#define VMW(n) asm volatile("s_waitcnt vmcnt(" #n ")" ::: "memory")
#define MFMA16(a, b, c) __builtin_amdgcn_mfma_f32_16x16x32_f16(a, b, c, 0, 0, 0)

struct Decay8 { float d[8]; };

// ---------------- prep kernels ----------------
__global__ __launch_bounds__(256) void cast_x_kernel(const float* __restrict__ in,
                                                     _Float16* __restrict__ out) {
    long i = (long)blockIdx.x * 256 + threadIdx.x;
    const f32x4* p = (const f32x4*)in;
    f32x4 a = p[i * 2], b = p[i * 2 + 1];
    half8 v;
    v[0] = (_Float16)a[0]; v[1] = (_Float16)a[1]; v[2] = (_Float16)a[2]; v[3] = (_Float16)a[3];
    v[4] = (_Float16)b[0]; v[5] = (_Float16)b[1]; v[6] = (_Float16)b[2]; v[7] = (_Float16)b[3];
    ((half8*)out)[i] = v;
}

// Wt[n][k] = (f16) W[k][n]  (no permutation; used for W_q)
__global__ __launch_bounds__(256) void transpose_cast_kernel(const float* __restrict__ W,
                                                             _Float16* __restrict__ Wt,
                                                             int K, int N) {
    __shared__ float tile[32][33];
    int n0 = blockIdx.x * 32, k0 = blockIdx.y * 32;
    int tx = threadIdx.x, ty = threadIdx.y;
    #pragma unroll
    for (int i = 0; i < 32; i += 8)
        tile[ty + i][tx] = W[(long)(k0 + ty + i) * N + n0 + tx];
    __syncthreads();
    #pragma unroll
    for (int i = 0; i < 32; i += 8)
        Wt[(long)(n0 + ty + i) * K + k0 + tx] = (_Float16)tile[tx][ty + i];
}

// Permuted variant for W_r/W_s (N=4096, K=1024): original col n=(u*8+tau) lands at
// permuted row (u>>4)*128 + tau*16 + (u&15), so one epilogue thread owns all 8 taus.
__global__ __launch_bounds__(256) void transpose_cast_perm_kernel(const float* __restrict__ W,
                                                                  _Float16* __restrict__ Wt,
                                                                  int rowbase) {
    const int K = 1024, N = 4096;
    __shared__ float tile[32][33];
    int n0 = blockIdx.x * 32, k0 = blockIdx.y * 32;
    int tx = threadIdx.x, ty = threadIdx.y;
    #pragma unroll
    for (int i = 0; i < 32; i += 8)
        tile[ty + i][tx] = W[(long)(k0 + ty + i) * N + n0 + tx];
    __syncthreads();
    #pragma unroll
    for (int i = 0; i < 32; i += 8) {
        int nl = n0 + ty + i;
        int u = nl >> 3, m = nl & 7;
        int nn = ((u >> 4) << 7) + (m << 4) + (u & 15);
        Wt[(long)(rowbase + nn) * K + k0 + tx] = (_Float16)tile[tx][ty + i];
    }
}

// ---------------- GEMM1 fused: 256x256 tile, 8 waves (4m x 2n, wave tile 64x128),
// 8-phase counted-vmcnt (6 barriers/K-tile); epilogue: thread-local softmax with
// h_hat prefetched during the final K-iteration (T14). nt=8 at t=0 (h==0). ----------
__global__ __launch_bounds__(512, 2) void gemm1_fused_kernel(
    const _Float16* __restrict__ A0, long lda0,      // x_t  (k<512)
    const _Float16* __restrict__ A1, long lda1,      // h    (k>=512)
    const _Float16* __restrict__ Wt,                  // 8192 x 1024 f16 (permuted)
    const float* __restrict__ b_r, const float* __restrict__ b_s,
    const _Float16* __restrict__ h_hat,               // (B,4096) f16, read-only
    _Float16* __restrict__ ctx,                       // (B,512)
    _Float16* __restrict__ s_buf,                     // (B,4096)
    int nt) {
    const float LT = 1.1512925464970228f;
    __shared__ __align__(16) _Float16 As[2][256 * 64];
    __shared__ __align__(16) _Float16 Bs[2][256 * 64];
    const int tid = threadIdx.x;
    const int lane = tid & 63;
    const int wave = tid >> 6;
    const int wm = wave >> 1, wn = wave & 1;          // 4 x 2 waves, tile 64 x 128
    const int l15 = lane & 15, lhi = lane >> 4, swz = lane & 7;
    const int g0 = (lhi ^ swz) * 8;
    const int g1 = ((lhi + 4) ^ swz) * 8;
    const int srow = tid >> 3;
    const int sg = (tid & 7) ^ (srow & 7);
    const int ldsdst = wave * 64 * 8;
    const long m0 = (long)blockIdx.y * 256;
    const long n0 = (long)blockIdx.x * 256;
    // epilogue constants (needed by the in-loop prefetch)
    const int r4 = lhi * 4;
    const int panel = (int)(n0 >> 7) + wn;             // global 128-col panel
    const bool is_r = panel < 32;
    const int u = (is_r ? panel : panel - 32) * 16 + l15;
    const long mrow = m0 + wm * 64;

#define STAGE_A(kt_, buf_, r_) do {                                             \
        int kt__ = (kt_);                                                       \
        const _Float16* s_; long lda_; int kofs_;                               \
        if (kt__ < 8) { s_ = A0; lda_ = lda0; kofs_ = kt__ * 64; }              \
        else          { s_ = A1; lda_ = lda1; kofs_ = kt__ * 64 - 512; }        \
        load_lds16(s_ + (m0 + (r_) * 64 + srow) * lda_ + kofs_ + sg * 8,        \
                   &As[buf_][(r_) * 4096 + ldsdst]);                            \
    } while (0)
#define STAGE_B(kt_, buf_, r_)                                                  \
        load_lds16(Wt + (n0 + (r_) * 64 + srow) * 1024 + (kt_) * 64 + sg * 8,   \
                   &Bs[buf_][(r_) * 4096 + ldsdst])

    f32x4 acc[4][8] = {};
    half8 pre_hh[4][4];                                // h_hat prefetch (r-panels)

    // Prologue: K0 full (buf0).  K1 (buf1): A r0-3 + B r0,r2 here; B r1,r3 at P0 of t=0.
    #pragma unroll
    for (int r = 0; r < 4; ++r) STAGE_A(0, 0, r);
    #pragma unroll
    for (int r = 0; r < 4; ++r) STAGE_B(0, 0, r);
    #pragma unroll
    for (int r = 0; r < 4; ++r) STAGE_A(1, 1, r);
    STAGE_B(1, 1, 0); STAGE_B(1, 1, 2);
    VMW(6);                                            // 14 issued; oldest 8 (=K0) retired
    BAR();

    #pragma unroll 1
    for (int t = 0; t < nt; ++t) {
        const int cur = t & 1, nxt = cur ^ 1;
        const _Float16* Ac = &As[cur][0];
        const _Float16* Bc = &Bs[cur][0];
        half8 af[4][2], bfa[2][2], bfb[2][2];

        // ---- P0: A frags + B j0-1.  No entry barrier (prev iter's VMW+exit-BAR). ----
        #pragma unroll
        for (int i = 0; i < 4; ++i) {
            const _Float16* p = Ac + (wm * 64 + i * 16 + l15) * 64;
            af[i][0] = *(const half8*)(p + g0);
            af[i][1] = *(const half8*)(p + g1);
        }
        #pragma unroll
        for (int j = 0; j < 2; ++j) {
            const _Float16* p = Bc + (wn * 128 + j * 16 + l15) * 64;
            bfa[j][0] = *(const half8*)(p + g0);
            bfa[j][1] = *(const half8*)(p + g1);
        }
        if (t + 1 < nt) { STAGE_B(t + 1, nxt, 1); STAGE_B(t + 1, nxt, 3); }
        LGKM0();
        __builtin_amdgcn_s_setprio(1);
        #pragma unroll
        for (int i = 0; i < 4; ++i)
            #pragma unroll
            for (int j = 0; j < 2; ++j) {
                acc[i][j] = MFMA16(af[i][0], bfa[j][0], acc[i][j]);
                acc[i][j] = MFMA16(af[i][1], bfa[j][1], acc[i][j]);
            }
        __builtin_amdgcn_s_setprio(0);
        BAR();                                         // exit: all waves past P0 A/B reads

        // ---- P1: B j2-3; stage A(t+2) r0,r1 ----
        #pragma unroll
        for (int j = 0; j < 2; ++j) {
            const _Float16* p = Bc + (wn * 128 + (2 + j) * 16 + l15) * 64;
            bfb[j][0] = *(const half8*)(p + g0);
            bfb[j][1] = *(const half8*)(p + g1);
        }
        if (t + 2 < nt) { STAGE_A(t + 2, cur, 0); STAGE_A(t + 2, cur, 1); }
        BAR(); LGKM0();
        __builtin_amdgcn_s_setprio(1);
        #pragma unroll
        for (int i = 0; i < 4; ++i)
            #pragma unroll
            for (int j = 0; j < 2; ++j) {
                acc[i][2 + j] = MFMA16(af[i][0], bfb[j][0], acc[i][2 + j]);
                acc[i][2 + j] = MFMA16(af[i][1], bfb[j][1], acc[i][2 + j]);
            }
        __builtin_amdgcn_s_setprio(0);
        BAR();

        // ---- P2: B j4-5; stage A(t+2) r2,r3.  No entry barrier. ----
        #pragma unroll
        for (int j = 0; j < 2; ++j) {
            const _Float16* p = Bc + (wn * 128 + (4 + j) * 16 + l15) * 64;
            bfa[j][0] = *(const half8*)(p + g0);
            bfa[j][1] = *(const half8*)(p + g1);
        }
        if (t + 2 < nt) { STAGE_A(t + 2, cur, 2); STAGE_A(t + 2, cur, 3); }
        LGKM0();
        __builtin_amdgcn_s_setprio(1);
        #pragma unroll
        for (int i = 0; i < 4; ++i)
            #pragma unroll
            for (int j = 0; j < 2; ++j) {
                acc[i][4 + j] = MFMA16(af[i][0], bfa[j][0], acc[i][4 + j]);
                acc[i][4 + j] = MFMA16(af[i][1], bfa[j][1], acc[i][4 + j]);
            }
        __builtin_amdgcn_s_setprio(0);
        BAR();                                         // exit: all waves past P0/P1 B reads

        // ---- P3: B j6-7; stage B(t+2) r0,r2.  Final iteration: prefetch h_hat
        // (no VMW executes after this point in the loop -> ledger untouched). ----
        if (t == nt - 1 && is_r) {
            #pragma unroll
            for (int i2 = 0; i2 < 4; ++i2)
                #pragma unroll
                for (int r2 = 0; r2 < 4; ++r2)
                    pre_hh[i2][r2] = *(const half8*)(h_hat +
                        (mrow + i2 * 16 + r4 + r2) * 4096 + u * 8);
        }
        #pragma unroll
        for (int j = 0; j < 2; ++j) {
            const _Float16* p = Bc + (wn * 128 + (6 + j) * 16 + l15) * 64;
            bfb[j][0] = *(const half8*)(p + g0);
            bfb[j][1] = *(const half8*)(p + g1);
        }
        if (t + 2 < nt) { STAGE_B(t + 2, cur, 0); STAGE_B(t + 2, cur, 2); }
        LGKM0();
        __builtin_amdgcn_s_setprio(1);
        #pragma unroll
        for (int i = 0; i < 4; ++i)
            #pragma unroll
            for (int j = 0; j < 2; ++j) {
                acc[i][6 + j] = MFMA16(af[i][0], bfb[j][0], acc[i][6 + j]);
                acc[i][6 + j] = MFMA16(af[i][1], bfb[j][1], acc[i][6 + j]);
            }
        __builtin_amdgcn_s_setprio(0);
        if (t + 2 < nt)      { VMW(6); }
        else if (t + 1 < nt) { VMW(0); }
        BAR();
    }

    // ---- fused epilogue: thread-local softmax over j (8 taus of group u) ----
    const float* bias = is_r ? b_r : b_s;
    f32x4 bl0 = *(const f32x4*)(bias + u * 8);
    f32x4 bl1 = *(const f32x4*)(bias + u * 8 + 4);

    #pragma unroll
    for (int i = 0; i < 4; ++i) {
        #pragma unroll
        for (int r = 0; r < 4; ++r) {
            long m = mrow + i * 16 + r4 + r;
            float z[8]; float zmax = -1e30f;
            #pragma unroll
            for (int j = 0; j < 8; ++j) {
                float v = acc[i][j][r] + (j < 4 ? bl0[j] : bl1[j - 4]);
                float d = v - (float)j * LT;
                z[j] = -d * d;
                zmax = fmaxf(zmax, z[j]);
            }
            float e[8]; float se = 0.f;
            #pragma unroll
            for (int j = 0; j < 8; ++j) { e[j] = __expf(z[j] - zmax); se += e[j]; }
            float inv = 1.f / se;
            if (is_r) {
                half8 hh = pre_hh[i][r];
                float c = 0.f;
                #pragma unroll
                for (int j = 0; j < 8; ++j) c += e[j] * (float)hh[j];
                ctx[m * 512 + u] = (_Float16)(c * inv);
            } else {
                half8 sv;
                #pragma unroll
                for (int j = 0; j < 8; ++j) sv[j] = (_Float16)(e[j] * inv);
                *(half8*)(s_buf + m * 4096 + u * 8) = sv;
            }
        }
    }
#undef STAGE_A
#undef STAGE_B
}

// ---------------- GEMM2 fused: 64x64 tile, 8 waves, dbuf counted-vmcnt;
// thread-local state update; s_buf/h_hat prefetched in final K-iteration (T14). ------
__global__ __launch_bounds__(512) void gemm2_fused_kernel(
    const _Float16* __restrict__ A0, long lda0,      // x_t
    const _Float16* __restrict__ A1, long lda1,      // ctx
    const _Float16* __restrict__ Wt,                  // 512 x 1024 f16
    const float* __restrict__ bias,
    const _Float16* __restrict__ s_buf,               // (B,4096) normalized s
    _Float16* __restrict__ h_hat,                     // (B,4096) f16, updated in place
    _Float16* __restrict__ hs_t,                      // (B,512) f16
    Decay8 dec, int nt) {
    __shared__ __align__(16) _Float16 As[2][64 * 64];
    __shared__ __align__(16) _Float16 Bs[2][64 * 64];
    const int tid = threadIdx.x;
    const int lane = tid & 63;
    const int wave = tid >> 6;
    const int wm = wave >> 1, wn = wave & 1;
    const int l15 = lane & 15, lhi = lane >> 4, swz = lane & 7;
    const int g0 = (lhi ^ swz) * 8;
    const int g1 = ((lhi + 4) ^ swz) * 8;
    const int srow = tid >> 3;
    const int sg = (tid & 7) ^ (srow & 7);
    const long m0 = (long)blockIdx.y * 64;
    const long n0 = (long)blockIdx.x * 64;
    const int r4 = lhi * 4;

#define STAGE2(kt_, buf_) do {                                                  \
        int kt__ = (kt_);                                                       \
        const _Float16* s_; long lda_; int kofs_;                               \
        if (kt__ < 8) { s_ = A0; lda_ = lda0; kofs_ = kt__ * 64; }              \
        else          { s_ = A1; lda_ = lda1; kofs_ = kt__ * 64 - 512; }        \
        load_lds16(s_ + (m0 + srow) * lda_ + kofs_ + sg * 8,                    \
                   &As[buf_][wave * 512]);                                      \
        load_lds16(Wt + (n0 + srow) * 1024 + kt__ * 64 + sg * 8,                \
                   &Bs[buf_][wave * 512]);                                      \
    } while (0)

    f32x4 acc[2] = {};
    half8 pre_s[2][4], pre_h[2][4];

    STAGE2(0, 0);
    #pragma unroll 1
    for (int kt = 0; kt < nt; ++kt) {
        const int cur = kt & 1;
        if (kt + 1 < nt) { STAGE2(kt + 1, cur ^ 1); VMW(2); }
        else             { VMW(0); }
        BAR();
        // Final iteration: prefetch epilogue operands (no VMW after this point).
        if (kt == nt - 1) {
            #pragma unroll
            for (int j2 = 0; j2 < 2; ++j2)
                #pragma unroll
                for (int r2 = 0; r2 < 4; ++r2) {
                    long b2 = m0 + wm * 16 + r4 + r2;
                    long u2 = n0 + wn * 32 + j2 * 16 + l15;
                    pre_s[j2][r2] = *(const half8*)(s_buf + b2 * 4096 + u2 * 8);
                    pre_h[j2][r2] = *(const half8*)(h_hat + b2 * 4096 + u2 * 8);
                }
        }
        const _Float16* Ac = &As[cur][0];
        const _Float16* Bc = &Bs[cur][0];
        half8 af[2], bf[2][2];
        {
            const _Float16* p = Ac + (wm * 16 + l15) * 64;
            af[0] = *(const half8*)(p + g0);
            af[1] = *(const half8*)(p + g1);
        }
        #pragma unroll
        for (int j = 0; j < 2; ++j) {
            const _Float16* p = Bc + (wn * 32 + j * 16 + l15) * 64;
            bf[j][0] = *(const half8*)(p + g0);
            bf[j][1] = *(const half8*)(p + g1);
        }
        LGKM0();
        #pragma unroll
        for (int j = 0; j < 2; ++j) {
            acc[j] = MFMA16(af[0], bf[j][0], acc[j]);
            acc[j] = MFMA16(af[1], bf[j][1], acc[j]);
        }
        BAR();
    }
#undef STAGE2

    #pragma unroll
    for (int j = 0; j < 2; ++j) {
        #pragma unroll
        for (int r = 0; r < 4; ++r) {
            long b = m0 + wm * 16 + r4 + r;
            long u = n0 + wn * 32 + j * 16 + l15;
            float q = tanhf(acc[j][r] + bias[u]);
            half8 s8 = pre_s[j][r];
            half8 h8 = pre_h[j][r];
            half8 hn;
            float hval = 0.f;
            #pragma unroll
            for (int m = 0; m < 8; ++m) {
                float sm = (float)s8[m];
                float x = ((1.f - sm) * (float)h8[m] + sm * q) * dec.d[m];
                hn[m] = (_Float16)x;
                hval += x;
            }
            *(half8*)(h_hat + b * 4096 + u * 8) = hn;
            hs_t[b * 512 + u] = (_Float16)hval;
        }
    }
}

// ---------------- final: out[b][t] = hs[t][b] @ W_o + b_o ----------------
__global__ __launch_bounds__(64) void out_proj_kernel(const _Float16* __restrict__ hs,
                                                      const float* __restrict__ W_o,
                                                      const float* __restrict__ b_o,
                                                      float* __restrict__ out) {
    const int bt = blockIdx.x;
    const int t = bt >> 11, b = bt & 2047;
    const int lane = threadIdx.x;
    half8 v = *(const half8*)(hs + ((long)t * 2048 + b) * 512 + lane * 8);
    float p0 = 0.f, p1 = 0.f, p2 = 0.f;
    #pragma unroll
    for (int m = 0; m < 8; ++m) {
        float hv = (float)v[m];
        int u = lane * 8 + m;
        p0 += hv * W_o[u * 3 + 0];
        p1 += hv * W_o[u * 3 + 1];
        p2 += hv * W_o[u * 3 + 2];
    }
    #pragma unroll
    for (int s = 32; s > 0; s >>= 1) {
        p0 += __shfl_down(p0, s);
        p1 += __shfl_down(p1, s);
        p2 += __shfl_down(p2, s);
    }
    if (lane == 0) {
        long o = ((long)b * T_ + t) * 3;
        out[o + 0] = p0 + b_o[0];
        out[o + 1] = p1 + b_o[1];
        out[o + 2] = p2 + b_o[2];
    }
}

// ---------------- host ----------------
extern "C" void kernel_launch(void* const* d_in, const int* in_sizes, int n_in,
                              void* d_out, int out_size, void* d_ws, size_t ws_size,
                              hipStream_t stream) {
    const float* x   = (const float*)d_in[0];
    const float* W_r = (const float*)d_in[1];
    const float* b_r = (const float*)d_in[2];
    const float* W_q = (const float*)d_in[3];
    const float* b_q = (const float*)d_in[4];
    const float* W_s = (const float*)d_in[5];
    const float* b_s = (const float*)d_in[6];
    const float* W_o = (const float*)d_in[7];
    const float* b_o = (const float*)d_in[8];
    float* out = (float*)d_out;

    char* ws = (char*)d_ws;
    size_t off = 0;
    _Float16* x_h   = (_Float16*)(ws + off); off += (size_t)B_ * T_ * F_ * 2;     // 33.5 MB
    _Float16* Wrs_t = (_Float16*)(ws + off); off += (size_t)8192 * 1024 * 2;      // 16.8 MB
    _Float16* Wq_t  = (_Float16*)(ws + off); off += (size_t)512 * 1024 * 2;       // 1 MB
    _Float16* s_buf = (_Float16*)(ws + off); off += (size_t)B_ * 4096 * 2;        // 16.8 MB
    _Float16* h_hat = (_Float16*)(ws + off); off += (size_t)B_ * 4096 * 2;        // 16.8 MB
    _Float16* ctx_h = (_Float16*)(ws + off); off += (size_t)B_ * U_ * 2;          // 2 MB
    _Float16* hs    = (_Float16*)(ws + off); off += (size_t)T_ * B_ * U_ * 2;     // 33.5 MB
    _Float16* zbuf  = (_Float16*)(ws + off); off += (size_t)B_ * U_ * 2;          // 2 MB
    if (ws_size < off) return;

    hipMemsetAsync(h_hat, 0, (size_t)B_ * 4096 * 2, stream);
    hipMemsetAsync(zbuf, 0, (size_t)B_ * U_ * 2, stream);

    cast_x_kernel<<<dim3((B_ * T_ * F_) / (256 * 8)), 256, 0, stream>>>(x, x_h);
    transpose_cast_perm_kernel<<<dim3(4096 / 32, 1024 / 32), dim3(32, 8), 0, stream>>>(W_r, Wrs_t, 0);
    transpose_cast_perm_kernel<<<dim3(4096 / 32, 1024 / 32), dim3(32, 8), 0, stream>>>(W_s, Wrs_t, 4096);
    transpose_cast_kernel<<<dim3(512 / 32, 1024 / 32), dim3(32, 8), 0, stream>>>(W_q, Wq_t, 1024, 512);

    Decay8 dec;
    for (int m = 0; m < 8; ++m) {
        float lt = (float)m * 1.1512925464970228f;
        dec.d[m] = expf(-0.04f / (expf(lt) + 1e-7f));
    }

    for (int t = 0; t < T_; ++t) {
        const _Float16* hprev = (t == 0) ? zbuf : hs + (size_t)(t - 1) * B_ * U_;
        const int nt = (t == 0) ? 8 : 16;   // t=0: h==0, ctx==0 -> x-half only
        gemm1_fused_kernel<<<dim3(8192 / 256, B_ / 256), 512, 0, stream>>>(
            x_h + (long)t * F_, (long)T_ * F_, hprev, U_, Wrs_t,
            b_r, b_s, h_hat, ctx_h, s_buf, nt);
        gemm2_fused_kernel<<<dim3(512 / 64, B_ / 64), 512, 0, stream>>>(
            x_h + (long)t * F_, (long)T_ * F_, ctx_h, U_, Wq_t,
            b_q, s_buf, h_hat, hs + (size_t)t * B_ * U_, dec, nt);
    }
    out_proj_kernel<<<dim3(B_ * T_), 64, 0, stream>>>(hs, W_o, b_o, out);
    (void)in_sizes; (void)n_in; (void)out_size;
}

// Round 12
// 988.187 us; speedup vs baseline: 2.0003x; 1.3478x over previous
//
#include <hip/hip_runtime.h>
#include <math.h>

#define B_ 2048
#define T_ 16
#define F_ 512
#define U_ 512
#define M_ 8

typedef _Float16 half8 __attribute__((ext_vector_type(8)));
typedef float f32x4 __attribute__((ext_vector_type(4)));

__device__ __forceinline__ void load_lds16(const _Float16* gsrc, _Float16* lds) {
    __builtin_amdgcn_global_load_lds(
        (const __attribute__((address_space(1))) void*)gsrc,
        (__attribute__((address_space(3))) void*)lds, 16, 0, 0);
}

#define BAR() __builtin_amdgcn_s_barrier()
#define LGKM0() asm volatile("s_waitcnt lgkmcnt(0)" ::: "memory")
#define VMW(n) asm volatile("s_waitcnt vmcnt(" #n ")" ::: "memory")
#define MFMA16(a, b, c) __builtin_amdgcn_mfma_f32_16x16x32_f16(a, b, c, 0, 0, 0)

struct Decay8 { float d[8]; };

// ---------------- prep kernels ----------------
__global__ __launch_bounds__(256) void cast_x_kernel(const float* __restrict__ in,
                                                     _Float16* __restrict__ out) {
    long i = (long)blockIdx.x * 256 + threadIdx.x;
    const f32x4* p = (const f32x4*)in;
    f32x4 a = p[i * 2], b = p[i * 2 + 1];
    half8 v;
    v[0] = (_Float16)a[0]; v[1] = (_Float16)a[1]; v[2] = (_Float16)a[2]; v[3] = (_Float16)a[3];
    v[4] = (_Float16)b[0]; v[5] = (_Float16)b[1]; v[6] = (_Float16)b[2]; v[7] = (_Float16)b[3];
    ((half8*)out)[i] = v;
}

// Wt[n][k] = (f16) W[k][n]  (no permutation; used for W_q)
__global__ __launch_bounds__(256) void transpose_cast_kernel(const float* __restrict__ W,
                                                             _Float16* __restrict__ Wt,
                                                             int K, int N) {
    __shared__ float tile[32][33];
    int n0 = blockIdx.x * 32, k0 = blockIdx.y * 32;
    int tx = threadIdx.x, ty = threadIdx.y;
    #pragma unroll
    for (int i = 0; i < 32; i += 8)
        tile[ty + i][tx] = W[(long)(k0 + ty + i) * N + n0 + tx];
    __syncthreads();
    #pragma unroll
    for (int i = 0; i < 32; i += 8)
        Wt[(long)(n0 + ty + i) * K + k0 + tx] = (_Float16)tile[tx][ty + i];
}

// Permuted variant for W_r/W_s (N=4096, K=1024): original col n=(u*8+tau) lands at
// permuted row (u>>4)*128 + tau*16 + (u&15), so one epilogue thread owns all 8 taus.
__global__ __launch_bounds__(256) void transpose_cast_perm_kernel(const float* __restrict__ W,
                                                                  _Float16* __restrict__ Wt,
                                                                  int rowbase) {
    const int K = 1024, N = 4096;
    __shared__ float tile[32][33];
    int n0 = blockIdx.x * 32, k0 = blockIdx.y * 32;
    int tx = threadIdx.x, ty = threadIdx.y;
    #pragma unroll
    for (int i = 0; i < 32; i += 8)
        tile[ty + i][tx] = W[(long)(k0 + ty + i) * N + n0 + tx];
    __syncthreads();
    #pragma unroll
    for (int i = 0; i < 32; i += 8) {
        int nl = n0 + ty + i;
        int u = nl >> 3, m = nl & 7;
        int nn = ((u >> 4) << 7) + (m << 4) + (u & 15);
        Wt[(long)(rowbase + nn) * K + k0 + tx] = (_Float16)tile[tx][ty + i];
    }
}

// ---------------- GEMM1 fused: 256x256 tile, 8 waves (4m x 2n, wave tile 64x128),
// 8-phase counted-vmcnt (6 barriers/K-tile); epilogue: thread-local softmax.
// nt=16 full K; nt=8 skips the h-part (t=0, h==0). ----------------------------------
__global__ __launch_bounds__(512, 2) void gemm1_fused_kernel(
    const _Float16* __restrict__ A0, long lda0,      // x_t  (k<512)
    const _Float16* __restrict__ A1, long lda1,      // h    (k>=512)
    const _Float16* __restrict__ Wt,                  // 8192 x 1024 f16 (permuted)
    const float* __restrict__ b_r, const float* __restrict__ b_s,
    const _Float16* __restrict__ h_hat,               // (B,4096) f16, read-only
    _Float16* __restrict__ ctx,                       // (B,512)
    _Float16* __restrict__ s_buf,                     // (B,4096)
    int nt) {
    const float LT = 1.1512925464970228f;
    __shared__ __align__(16) _Float16 As[2][256 * 64];
    __shared__ __align__(16) _Float16 Bs[2][256 * 64];
    const int tid = threadIdx.x;
    const int lane = tid & 63;
    const int wave = tid >> 6;
    const int wm = wave >> 1, wn = wave & 1;          // 4 x 2 waves, tile 64 x 128
    const int l15 = lane & 15, lhi = lane >> 4, swz = lane & 7;
    const int g0 = (lhi ^ swz) * 8;
    const int g1 = ((lhi + 4) ^ swz) * 8;
    const int srow = tid >> 3;
    const int sg = (tid & 7) ^ (srow & 7);
    const int ldsdst = wave * 64 * 8;
    const long m0 = (long)blockIdx.y * 256;
    const long n0 = (long)blockIdx.x * 256;

#define STAGE_A(kt_, buf_, r_) do {                                             \
        int kt__ = (kt_);                                                       \
        const _Float16* s_; long lda_; int kofs_;                               \
        if (kt__ < 8) { s_ = A0; lda_ = lda0; kofs_ = kt__ * 64; }              \
        else          { s_ = A1; lda_ = lda1; kofs_ = kt__ * 64 - 512; }        \
        load_lds16(s_ + (m0 + (r_) * 64 + srow) * lda_ + kofs_ + sg * 8,        \
                   &As[buf_][(r_) * 4096 + ldsdst]);                            \
    } while (0)
#define STAGE_B(kt_, buf_, r_)                                                  \
        load_lds16(Wt + (n0 + (r_) * 64 + srow) * 1024 + (kt_) * 64 + sg * 8,   \
                   &Bs[buf_][(r_) * 4096 + ldsdst])

    f32x4 acc[4][8] = {};

    // Prologue: K0 full (buf0).  K1 (buf1): A r0-3 + B r0,r2 here; B r1,r3 at P0 of t=0.
    #pragma unroll
    for (int r = 0; r < 4; ++r) STAGE_A(0, 0, r);
    #pragma unroll
    for (int r = 0; r < 4; ++r) STAGE_B(0, 0, r);
    #pragma unroll
    for (int r = 0; r < 4; ++r) STAGE_A(1, 1, r);
    STAGE_B(1, 1, 0); STAGE_B(1, 1, 2);
    VMW(6);                                            // 14 issued; oldest 8 (=K0) retired
    BAR();

    #pragma unroll 1
    for (int t = 0; t < nt; ++t) {
        const int cur = t & 1, nxt = cur ^ 1;
        const _Float16* Ac = &As[cur][0];
        const _Float16* Bc = &Bs[cur][0];
        half8 af[4][2], bfa[2][2], bfb[2][2];

        // ---- P0: A frags + B j0-1.  No entry barrier (prev iter's VMW+exit-BAR). ----
        #pragma unroll
        for (int i = 0; i < 4; ++i) {
            const _Float16* p = Ac + (wm * 64 + i * 16 + l15) * 64;
            af[i][0] = *(const half8*)(p + g0);
            af[i][1] = *(const half8*)(p + g1);
        }
        #pragma unroll
        for (int j = 0; j < 2; ++j) {
            const _Float16* p = Bc + (wn * 128 + j * 16 + l15) * 64;
            bfa[j][0] = *(const half8*)(p + g0);
            bfa[j][1] = *(const half8*)(p + g1);
        }
        if (t + 1 < nt) { STAGE_B(t + 1, nxt, 1); STAGE_B(t + 1, nxt, 3); }
        LGKM0();
        __builtin_amdgcn_s_setprio(1);
        #pragma unroll
        for (int i = 0; i < 4; ++i)
            #pragma unroll
            for (int j = 0; j < 2; ++j) {
                acc[i][j] = MFMA16(af[i][0], bfa[j][0], acc[i][j]);
                acc[i][j] = MFMA16(af[i][1], bfa[j][1], acc[i][j]);
            }
        __builtin_amdgcn_s_setprio(0);
        BAR();                                         // exit: all waves past P0 A/B reads

        // ---- P1: B j2-3; stage A(t+2) r0,r1 ----
        #pragma unroll
        for (int j = 0; j < 2; ++j) {
            const _Float16* p = Bc + (wn * 128 + (2 + j) * 16 + l15) * 64;
            bfb[j][0] = *(const half8*)(p + g0);
            bfb[j][1] = *(const half8*)(p + g1);
        }
        if (t + 2 < nt) { STAGE_A(t + 2, cur, 0); STAGE_A(t + 2, cur, 1); }
        BAR(); LGKM0();
        __builtin_amdgcn_s_setprio(1);
        #pragma unroll
        for (int i = 0; i < 4; ++i)
            #pragma unroll
            for (int j = 0; j < 2; ++j) {
                acc[i][2 + j] = MFMA16(af[i][0], bfb[j][0], acc[i][2 + j]);
                acc[i][2 + j] = MFMA16(af[i][1], bfb[j][1], acc[i][2 + j]);
            }
        __builtin_amdgcn_s_setprio(0);
        BAR();

        // ---- P2: B j4-5; stage A(t+2) r2,r3.  No entry barrier. ----
        #pragma unroll
        for (int j = 0; j < 2; ++j) {
            const _Float16* p = Bc + (wn * 128 + (4 + j) * 16 + l15) * 64;
            bfa[j][0] = *(const half8*)(p + g0);
            bfa[j][1] = *(const half8*)(p + g1);
        }
        if (t + 2 < nt) { STAGE_A(t + 2, cur, 2); STAGE_A(t + 2, cur, 3); }
        LGKM0();
        __builtin_amdgcn_s_setprio(1);
        #pragma unroll
        for (int i = 0; i < 4; ++i)
            #pragma unroll
            for (int j = 0; j < 2; ++j) {
                acc[i][4 + j] = MFMA16(af[i][0], bfa[j][0], acc[i][4 + j]);
                acc[i][4 + j] = MFMA16(af[i][1], bfa[j][1], acc[i][4 + j]);
            }
        __builtin_amdgcn_s_setprio(0);
        BAR();                                         // exit: all waves past P0/P1 B reads

        // ---- P3: B j6-7; stage B(t+2) r0,r2 (read at P0/P1 by all waves -> dead). ----
        #pragma unroll
        for (int j = 0; j < 2; ++j) {
            const _Float16* p = Bc + (wn * 128 + (6 + j) * 16 + l15) * 64;
            bfb[j][0] = *(const half8*)(p + g0);
            bfb[j][1] = *(const half8*)(p + g1);
        }
        if (t + 2 < nt) { STAGE_B(t + 2, cur, 0); STAGE_B(t + 2, cur, 2); }
        LGKM0();
        __builtin_amdgcn_s_setprio(1);
        #pragma unroll
        for (int i = 0; i < 4; ++i)
            #pragma unroll
            for (int j = 0; j < 2; ++j) {
                acc[i][6 + j] = MFMA16(af[i][0], bfb[j][0], acc[i][6 + j]);
                acc[i][6 + j] = MFMA16(af[i][1], bfb[j][1], acc[i][6 + j]);
            }
        __builtin_amdgcn_s_setprio(0);
        if (t + 2 < nt)      { VMW(6); }
        else if (t + 1 < nt) { VMW(0); }
        BAR();
    }

    // ---- fused epilogue: thread-local softmax over j (8 taus of group u) ----
    const int r4 = lhi * 4;
    const int panel = (int)(n0 >> 7) + wn;             // global 128-col panel
    const bool is_r = panel < 32;
    const int u = (is_r ? panel : panel - 32) * 16 + l15;
    const float* bias = is_r ? b_r : b_s;
    f32x4 bl0 = *(const f32x4*)(bias + u * 8);
    f32x4 bl1 = *(const f32x4*)(bias + u * 8 + 4);

    #pragma unroll
    for (int i = 0; i < 4; ++i) {
        #pragma unroll
        for (int r = 0; r < 4; ++r) {
            long m = m0 + wm * 64 + i * 16 + r4 + r;
            float z[8]; float zmax = -1e30f;
            #pragma unroll
            for (int j = 0; j < 8; ++j) {
                float v = acc[i][j][r] + (j < 4 ? bl0[j] : bl1[j - 4]);
                float d = v - (float)j * LT;
                z[j] = -d * d;
                zmax = fmaxf(zmax, z[j]);
            }
            float e[8]; float se = 0.f;
            #pragma unroll
            for (int j = 0; j < 8; ++j) { e[j] = __expf(z[j] - zmax); se += e[j]; }
            float inv = 1.f / se;
            if (is_r) {
                half8 hh = *(const half8*)(h_hat + m * 4096 + u * 8);
                float c = 0.f;
                #pragma unroll
                for (int j = 0; j < 8; ++j) c += e[j] * (float)hh[j];
                ctx[m * 512 + u] = (_Float16)(c * inv);
            } else {
                half8 sv;
                #pragma unroll
                for (int j = 0; j < 8; ++j) sv[j] = (_Float16)(e[j] * inv);
                *(half8*)(s_buf + m * 4096 + u * 8) = sv;
            }
        }
    }
#undef STAGE_A
#undef STAGE_B
}

// ---------------- GEMM2 fused: 64x64 tile, 8 waves, dbuf counted-vmcnt;
// thread-local state update in epilogue. nt=8 skips the ctx half (t=0). --------------
__global__ __launch_bounds__(512) void gemm2_fused_kernel(
    const _Float16* __restrict__ A0, long lda0,      // x_t
    const _Float16* __restrict__ A1, long lda1,      // ctx
    const _Float16* __restrict__ Wt,                  // 512 x 1024 f16
    const float* __restrict__ bias,
    const _Float16* __restrict__ s_buf,               // (B,4096) normalized s
    _Float16* __restrict__ h_hat,                     // (B,4096) f16, updated in place
    _Float16* __restrict__ hs_t,                      // (B,512) f16
    Decay8 dec, int nt) {
    __shared__ __align__(16) _Float16 As[2][64 * 64];
    __shared__ __align__(16) _Float16 Bs[2][64 * 64];
    const int tid = threadIdx.x;
    const int lane = tid & 63;
    const int wave = tid >> 6;
    const int wm = wave >> 1, wn = wave & 1;
    const int l15 = lane & 15, lhi = lane >> 4, swz = lane & 7;
    const int g0 = (lhi ^ swz) * 8;
    const int g1 = ((lhi + 4) ^ swz) * 8;
    const int srow = tid >> 3;
    const int sg = (tid & 7) ^ (srow & 7);
    const long m0 = (long)blockIdx.y * 64;
    const long n0 = (long)blockIdx.x * 64;

#define STAGE2(kt_, buf_) do {                                                  \
        int kt__ = (kt_);                                                       \
        const _Float16* s_; long lda_; int kofs_;                               \
        if (kt__ < 8) { s_ = A0; lda_ = lda0; kofs_ = kt__ * 64; }              \
        else          { s_ = A1; lda_ = lda1; kofs_ = kt__ * 64 - 512; }        \
        load_lds16(s_ + (m0 + srow) * lda_ + kofs_ + sg * 8,                    \
                   &As[buf_][wave * 512]);                                      \
        load_lds16(Wt + (n0 + srow) * 1024 + kt__ * 64 + sg * 8,                \
                   &Bs[buf_][wave * 512]);                                      \
    } while (0)

    f32x4 acc[2] = {};

    STAGE2(0, 0);
    #pragma unroll 1
    for (int kt = 0; kt < nt; ++kt) {
        const int cur = kt & 1;
        if (kt + 1 < nt) { STAGE2(kt + 1, cur ^ 1); VMW(2); }
        else             { VMW(0); }
        BAR();
        const _Float16* Ac = &As[cur][0];
        const _Float16* Bc = &Bs[cur][0];
        half8 af[2], bf[2][2];
        {
            const _Float16* p = Ac + (wm * 16 + l15) * 64;
            af[0] = *(const half8*)(p + g0);
            af[1] = *(const half8*)(p + g1);
        }
        #pragma unroll
        for (int j = 0; j < 2; ++j) {
            const _Float16* p = Bc + (wn * 32 + j * 16 + l15) * 64;
            bf[j][0] = *(const half8*)(p + g0);
            bf[j][1] = *(const half8*)(p + g1);
        }
        LGKM0();
        #pragma unroll
        for (int j = 0; j < 2; ++j) {
            acc[j] = MFMA16(af[0], bf[j][0], acc[j]);
            acc[j] = MFMA16(af[1], bf[j][1], acc[j]);
        }
        BAR();
    }
#undef STAGE2

    const int r4 = lhi * 4;
    const int c16 = lane & 15;
    #pragma unroll
    for (int j = 0; j < 2; ++j) {
        #pragma unroll
        for (int r = 0; r < 4; ++r) {
            long b = m0 + wm * 16 + r4 + r;
            long u = n0 + wn * 32 + j * 16 + c16;
            float q = tanhf(acc[j][r] + bias[u]);
            half8 s8 = *(const half8*)(s_buf + b * 4096 + u * 8);
            half8 h8 = *(const half8*)(h_hat + b * 4096 + u * 8);
            half8 hn;
            float hval = 0.f;
            #pragma unroll
            for (int m = 0; m < 8; ++m) {
                float sm = (float)s8[m];
                float x = ((1.f - sm) * (float)h8[m] + sm * q) * dec.d[m];
                hn[m] = (_Float16)x;
                hval += x;
            }
            *(half8*)(h_hat + b * 4096 + u * 8) = hn;
            hs_t[b * 512 + u] = (_Float16)hval;
        }
    }
}

// ---------------- final: out[b][t] = hs[t][b] @ W_o + b_o ----------------
__global__ __launch_bounds__(64) void out_proj_kernel(const _Float16* __restrict__ hs,
                                                      const float* __restrict__ W_o,
                                                      const float* __restrict__ b_o,
                                                      float* __restrict__ out) {
    const int bt = blockIdx.x;
    const int t = bt >> 11, b = bt & 2047;
    const int lane = threadIdx.x;
    half8 v = *(const half8*)(hs + ((long)t * 2048 + b) * 512 + lane * 8);
    float p0 = 0.f, p1 = 0.f, p2 = 0.f;
    #pragma unroll
    for (int m = 0; m < 8; ++m) {
        float hv = (float)v[m];
        int u = lane * 8 + m;
        p0 += hv * W_o[u * 3 + 0];
        p1 += hv * W_o[u * 3 + 1];
        p2 += hv * W_o[u * 3 + 2];
    }
    #pragma unroll
    for (int s = 32; s > 0; s >>= 1) {
        p0 += __shfl_down(p0, s);
        p1 += __shfl_down(p1, s);
        p2 += __shfl_down(p2, s);
    }
    if (lane == 0) {
        long o = ((long)b * T_ + t) * 3;
        out[o + 0] = p0 + b_o[0];
        out[o + 1] = p1 + b_o[1];
        out[o + 2] = p2 + b_o[2];
    }
}

// ---------------- host ----------------
extern "C" void kernel_launch(void* const* d_in, const int* in_sizes, int n_in,
                              void* d_out, int out_size, void* d_ws, size_t ws_size,
                              hipStream_t stream) {
    const float* x   = (const float*)d_in[0];
    const float* W_r = (const float*)d_in[1];
    const float* b_r = (const float*)d_in[2];
    const float* W_q = (const float*)d_in[3];
    const float* b_q = (const float*)d_in[4];
    const float* W_s = (const float*)d_in[5];
    const float* b_s = (const float*)d_in[6];
    const float* W_o = (const float*)d_in[7];
    const float* b_o = (const float*)d_in[8];
    float* out = (float*)d_out;

    char* ws = (char*)d_ws;
    size_t off = 0;
    _Float16* x_h   = (_Float16*)(ws + off); off += (size_t)B_ * T_ * F_ * 2;     // 33.5 MB
    _Float16* Wrs_t = (_Float16*)(ws + off); off += (size_t)8192 * 1024 * 2;      // 16.8 MB
    _Float16* Wq_t  = (_Float16*)(ws + off); off += (size_t)512 * 1024 * 2;       // 1 MB
    _Float16* s_buf = (_Float16*)(ws + off); off += (size_t)B_ * 4096 * 2;        // 16.8 MB
    _Float16* h_hat = (_Float16*)(ws + off); off += (size_t)B_ * 4096 * 2;        // 16.8 MB
    _Float16* ctx_h = (_Float16*)(ws + off); off += (size_t)B_ * U_ * 2;          // 2 MB
    _Float16* hs    = (_Float16*)(ws + off); off += (size_t)T_ * B_ * U_ * 2;     // 33.5 MB
    _Float16* zbuf  = (_Float16*)(ws + off); off += (size_t)B_ * U_ * 2;          // 2 MB
    if (ws_size < off) return;

    hipMemsetAsync(h_hat, 0, (size_t)B_ * 4096 * 2, stream);
    hipMemsetAsync(zbuf, 0, (size_t)B_ * U_ * 2, stream);

    cast_x_kernel<<<dim3((B_ * T_ * F_) / (256 * 8)), 256, 0, stream>>>(x, x_h);
    transpose_cast_perm_kernel<<<dim3(4096 / 32, 1024 / 32), dim3(32, 8), 0, stream>>>(W_r, Wrs_t, 0);
    transpose_cast_perm_kernel<<<dim3(4096 / 32, 1024 / 32), dim3(32, 8), 0, stream>>>(W_s, Wrs_t, 4096);
    transpose_cast_kernel<<<dim3(512 / 32, 1024 / 32), dim3(32, 8), 0, stream>>>(W_q, Wq_t, 1024, 512);

    Decay8 dec;
    for (int m = 0; m < 8; ++m) {
        float lt = (float)m * 1.1512925464970228f;
        dec.d[m] = expf(-0.04f / (expf(lt) + 1e-7f));
    }

    for (int t = 0; t < T_; ++t) {
        const _Float16* hprev = (t == 0) ? zbuf : hs + (size_t)(t - 1) * B_ * U_;
        const int nt = (t == 0) ? 8 : 16;   // t=0: h==0, ctx==0 -> x-half only
        gemm1_fused_kernel<<<dim3(8192 / 256, B_ / 256), 512, 0, stream>>>(
            x_h + (long)t * F_, (long)T_ * F_, hprev, U_, Wrs_t,
            b_r, b_s, h_hat, ctx_h, s_buf, nt);
        gemm2_fused_kernel<<<dim3(512 / 64, B_ / 64), 512, 0, stream>>>(
            x_h + (long)t * F_, (long)T_ * F_, ctx_h, U_, Wq_t,
            b_q, s_buf, h_hat, hs + (size_t)t * B_ * U_, dec, nt);
    }
    out_proj_kernel<<<dim3(B_ * T_), 64, 0, stream>>>(hs, W_o, b_o, out);
    (void)in_sizes; (void)n_in; (void)out_size;
}